// Round 5
// baseline (3798.278 us; speedup 1.0000x reference)
//
#include <hip/hip_runtime.h>
#include <stdint.h>

#define T_LEN 1024
#define B_SZ  64
#define I_SZ  256
#define H_SZ  512
#define O_SZ  128

// workspace layout (bytes)
#define FLAG_OFF 0ull                 // 8 chains * 16 WGs * 4B = 512 (monotone step flags)
#define HB_OFF  65536ull              // 2 bufs * 2 dir * 64 * 512 * 2B = 262144 (packed bf16 h)
#define Y_OFF   327680ull             // 64*1024*1024*2 = 134217728
#define XBF_OFF 134545408ull          // 64*1024*256*2  = 33554432
#define MEMSET_BYTES 327680ull        // flags + h buffers

typedef __attribute__((ext_vector_type(8))) short short8;
typedef __attribute__((ext_vector_type(4))) float f32x4;

__device__ __forceinline__ unsigned short f2bf(float f) {
  unsigned u = __float_as_uint(f);
  u += 0x7fffu + ((u >> 16) & 1u);
  return (unsigned short)(u >> 16);
}
__device__ __forceinline__ ushort4 cvt4(float4 v) {
  ushort4 p;
  p.x = f2bf(v.x); p.y = f2bf(v.y); p.z = f2bf(v.z); p.w = f2bf(v.w);
  return p;
}
__device__ __forceinline__ float sigm(float x) { return 1.0f / (1.0f + __expf(-x)); }
__device__ __forceinline__ float tanh_f(float x) { return 1.0f - 2.0f / (1.0f + __expf(2.0f * x)); }

// ---------------- input fp32 -> bf16 conversion ----------------
__global__ void __launch_bounds__(256) cvt_x(const float* __restrict__ x,
                                             unsigned short* __restrict__ xb) {
  size_t i = ((size_t)blockIdx.x * 256 + threadIdx.x) * 8;
  float4 a = *(const float4*)(x + i);
  float4 b = *(const float4*)(x + i + 4);
  *(ushort4*)(xb + i)     = cvt4(a);
  *(ushort4*)(xb + i + 4) = cvt4(b);
}

// ---------------- persistent bidirectional LSTM scan ----------------
// grid 128 = 8 chains (dir x 4 batch-groups of 16) x 16 unit-group WGs (32
// units each), 512 thr. PROVEN R3 protocol: h stored packed bf16 with
// agent-scope sc1 stores; s_waitcnt(0) drain; per-WG monotone flag; all-wave
// 16-lane flag poll. R4's reshape + staging overlap applied; y store moved
// after the flag so its ack is off the drain path.
__global__ void __launch_bounds__(512, 2)
lstm_scan(const unsigned short* __restrict__ xbf,
          const float* __restrict__ WihF, const float* __restrict__ WhhF,
          const float* __restrict__ bihF, const float* __restrict__ bhhF,
          const float* __restrict__ WihB, const float* __restrict__ WhhB,
          const float* __restrict__ bihB, const float* __restrict__ bhhB,
          unsigned char* __restrict__ ws, float* __restrict__ out)
{
  __shared__ unsigned short xs[2][16][264];  // x double buffer (16 batch x 256)
  __shared__ unsigned short hs[16][520];     // h staging (16 batch x 512)
  __shared__ float gbuf[4][16][36];          // [gate][batch][unit 0..31]
  __shared__ float cst[16][36];              // cell state fp32

  const int tid  = threadIdx.x;
  const int lane = tid & 63;
  const int wave = tid >> 6;
  const int nl   = lane & 15;
  const int q16  = lane >> 4;

  const int wg   = blockIdx.x;
  const int d    = wg >> 6;              // 0 fwd, 1 bwd
  const int b0   = ((wg >> 4) & 3) * 16; // batch-group base (16 batches)
  const int u0   = (wg & 15) * 32;       // unit-group base (32 units)
  const int grp  = wg >> 4;              // chain id (0..7)
  const int wgid = wg & 15;              // id within chain

  const float* Wih = d ? WihB : WihF;
  const float* Whh = d ? WhhB : WhhF;
  const float* bih = d ? bihB : bihF;
  const float* bhh = d ? bhhB : bhhF;

  const int gate = wave >> 1;          // 0=i 1=f 2=g 3=o
  const int usub = (wave & 1) * 16;    // which 16 of the WG's 32 units

  // ---- preload B fragments: wfrag[0..7]=Wih(K=256), [8..23]=Whh(K=512) ----
  short8 wfrag[24];
  {
    const int row = gate * H_SZ + u0 + usub + nl;
    const float* wi = Wih + (size_t)row * I_SZ;
    const float* wh = Whh + (size_t)row * H_SZ;
#pragma unroll
    for (int kk = 0; kk < 24; ++kk) {
      const float* src = (kk < 8) ? (wi + kk * 32 + q16 * 8)
                                  : (wh + (kk - 8) * 32 + q16 * 8);
      float4 v0 = ((const float4*)src)[0];
      float4 v1 = ((const float4*)src)[1];
      short8 w;
      w[0] = (short)f2bf(v0.x); w[1] = (short)f2bf(v0.y);
      w[2] = (short)f2bf(v0.z); w[3] = (short)f2bf(v0.w);
      w[4] = (short)f2bf(v1.x); w[5] = (short)f2bf(v1.y);
      w[6] = (short)f2bf(v1.z); w[7] = (short)f2bf(v1.w);
      wfrag[kk] = w;
    }
  }
  const float bias = bih[gate * H_SZ + u0 + usub + nl] + bhh[gate * H_SZ + u0 + usub + nl];

  cst[tid >> 5][tid & 31] = 0.0f;

  unsigned* flags  = (unsigned*)(ws + FLAG_OFF);
  unsigned* hbuf32 = (unsigned*)(ws + HB_OFF);
  unsigned* ybuf32 = (unsigned*)(ws + Y_OFF);
  unsigned* hs32   = (unsigned*)hs;

  const int sm = tid >> 5, sseg = tid & 31;  // x-staging coords (16 x 32)

  // ---- prologue: stage x(t0) into xs[0], xacc for s=0, prefetch x(t1) ----
  {
    const int t0 = d ? (T_LEN - 1) : 0;
    uint4 a = *(const uint4*)(xbf + ((size_t)(b0 + sm) * T_LEN + t0) * I_SZ + sseg * 8);
    *(uint4*)(&xs[0][sm][sseg * 8]) = a;
  }
  __syncthreads();
  f32x4 xacc = {0.f, 0.f, 0.f, 0.f};
  {
    const unsigned short* xr = &xs[0][nl][q16 * 8];
#pragma unroll
    for (int kk = 0; kk < 8; ++kk) {
      short8 a = *(const short8*)(xr + kk * 32);
      xacc = __builtin_amdgcn_mfma_f32_16x16x32_bf16(a, wfrag[kk], xacc, 0, 0, 0);
    }
  }
  uint4 px;
  {
    const int t1 = d ? (T_LEN - 2) : 1;
    px = *(const uint4*)(xbf + ((size_t)(b0 + sm) * T_LEN + t1) * I_SZ + sseg * 8);
  }

  for (int s = 0; s < T_LEN; ++s) {
    const int t   = d ? (T_LEN - 1 - s) : s;
    const int cur = s & 1, nxt = cur ^ 1;
    const int rb  = cur ^ 1, wb = cur;

    // ---- wait for producers of h_{s-1}: all-wave 16-lane flag poll ----
    if (s > 0) {
      const unsigned tgt = (unsigned)s;
      const unsigned* fl = flags + grp * 16;
      for (;;) {
        unsigned f = (lane < 16)
          ? __hip_atomic_load(fl + lane, __ATOMIC_RELAXED, __HIP_MEMORY_SCOPE_AGENT)
          : tgt;
        if (__all((int)(f >= tgt))) break;
      }
    }

    // ---- load h_{s-1} (packed bf16) from MALL; overlap x staging ----
    {
      unsigned hv[8];
      const unsigned* hb = hbuf32 + (size_t)((rb * 2 + d) * B_SZ + b0) * 256;
#pragma unroll
      for (int j = 0; j < 8; ++j)
        hv[j] = __hip_atomic_load(hb + j * 512 + tid, __ATOMIC_RELAXED, __HIP_MEMORY_SCOPE_AGENT);
      if (s < T_LEN - 1)
        *(uint4*)(&xs[nxt][sm][sseg * 8]) = px;
#pragma unroll
      for (int j = 0; j < 8; ++j) {
        int lin = j * 512 + tid;
        hs32[(lin >> 8) * 260 + (lin & 255)] = hv[j];
      }
    }
    __syncthreads();

    // ---- h-part MFMAs (dual chains), seeded with precomputed x-part ----
    f32x4 acc0 = xacc, acc1 = {0.f, 0.f, 0.f, 0.f};
    {
      const unsigned short* ar = &hs[nl][q16 * 8];
#pragma unroll
      for (int kk = 0; kk < 16; kk += 2) {
        short8 a0 = *(const short8*)(ar + kk * 32);
        short8 a1 = *(const short8*)(ar + (kk + 1) * 32);
        acc0 = __builtin_amdgcn_mfma_f32_16x16x32_bf16(a0, wfrag[8 + kk], acc0, 0, 0, 0);
        acc1 = __builtin_amdgcn_mfma_f32_16x16x32_bf16(a1, wfrag[9 + kk], acc1, 0, 0, 0);
      }
      acc0 += acc1;
    }

    // ---- bias + activation -> gbuf ----
#pragma unroll
    for (int r = 0; r < 4; ++r) {
      float v = acc0[r] + bias;
      v = (gate == 2) ? tanh_f(v) : sigm(v);
      gbuf[gate][q16 * 4 + r][usub + nl] = v;
    }
    __syncthreads();

    // ---- cell/hidden update; h store (sc1); y deferred past the flag ----
    unsigned packed; size_t yi;
    {
      int m = tid >> 5, n = tid & 31;
      float gi = gbuf[0][m][n], gf = gbuf[1][m][n];
      float gg = gbuf[2][m][n], go = gbuf[3][m][n];
      float c = gf * cst[m][n] + gi * gg;
      cst[m][n] = c;
      float h = go * tanh_f(c);
      unsigned hbits = f2bf(h);
      unsigned other = __shfl_xor(hbits, 1);
      packed = hbits | (other << 16);
      yi = ((size_t)(b0 + m) * T_LEN + t) * 512 + (d * H_SZ + u0 + n) / 2;
      if ((tid & 1) == 0) {
        size_t hi = (size_t)((wb * 2 + d) * B_SZ + b0 + m) * 256 + (u0 + n) / 2;
        __hip_atomic_store(hbuf32 + hi, packed, __ATOMIC_RELAXED, __HIP_MEMORY_SCOPE_AGENT);
      }
      if (s == T_LEN - 1) {
        size_t hi = (size_t)(d * B_SZ + b0 + m) * H_SZ + u0 + n;
        out[8388608ull + hi] = h;            // h_n
        out[8388608ull + 65536ull + hi] = c; // c_n
      }
    }

    if (s < T_LEN - 1) {
      // ---- drain h stores, then raise this WG's flag ----
      __builtin_amdgcn_s_waitcnt(0);
      __syncthreads();
      if (tid == 0)
        __hip_atomic_store(flags + grp * 16 + wgid, (unsigned)(s + 1),
                           __ATOMIC_RELAXED, __HIP_MEMORY_SCOPE_AGENT);
    }

    // ---- y store (off the drain path; only read after kernel end) ----
    if ((tid & 1) == 0)
      ybuf32[yi] = packed;

    if (s < T_LEN - 1) {
      // ---- prefetch x for s+2 (stays outstanding through next poll) ----
      if (s + 2 < T_LEN) {
        const int t2 = d ? (T_LEN - 3 - s) : (s + 2);
        px = *(const uint4*)(xbf + ((size_t)(b0 + sm) * T_LEN + t2) * I_SZ + sseg * 8);
      }
      // ---- precompute x-part MFMAs for step s+1 (off critical path) ----
      f32x4 xa = {0.f, 0.f, 0.f, 0.f};
      const unsigned short* xr = &xs[nxt][nl][q16 * 8];
#pragma unroll
      for (int kk = 0; kk < 8; ++kk) {
        short8 a = *(const short8*)(xr + kk * 32);
        xa = __builtin_amdgcn_mfma_f32_16x16x32_bf16(a, wfrag[kk], xa, 0, 0, 0);
      }
      xacc = xa;
    }
  }
}

// ---------------- output projection: out = y @ W_out^T + b_out ----------------
__global__ void __launch_bounds__(256, 1)
proj(const unsigned short* __restrict__ y, const float* __restrict__ Wout,
     const float* __restrict__ bout, float* __restrict__ out)
{
  __shared__ unsigned short ys[128 * 264];
  __shared__ unsigned short wst[128 * 264];

  const int tid  = threadIdx.x;
  const int wave = tid >> 6;
  const int lane = tid & 63;
  const int nl   = lane & 15;
  const int q16  = lane >> 4;
  const int m0   = blockIdx.x * 128;

  f32x4 acc[2][8];
#pragma unroll
  for (int a = 0; a < 2; ++a)
#pragma unroll
    for (int b = 0; b < 8; ++b) acc[a][b] = (f32x4){0.f, 0.f, 0.f, 0.f};

  for (int k0 = 0; k0 < 1024; k0 += 256) {
    {
      int r = tid >> 1, half = tid & 1;
      const uint4* src = (const uint4*)(y + (size_t)(m0 + r) * 1024 + k0 + half * 128);
      uint4* dst = (uint4*)(ys + r * 264 + half * 128);
#pragma unroll
      for (int q = 0; q < 16; ++q) dst[q] = src[q];
    }
    {
      int r = tid >> 1, half = tid & 1;
      const float4* src = (const float4*)(Wout + (size_t)r * 1024 + k0 + half * 128);
      unsigned short* wd = wst + r * 264 + half * 128;
#pragma unroll
      for (int q = 0; q < 32; ++q) *(ushort4*)(wd + q * 4) = cvt4(src[q]);
    }
    __syncthreads();

#pragma unroll
    for (int kk = 0; kk < 8; ++kk) {
      const int ko = kk * 32 + q16 * 8;
      short8 bfr[8];
#pragma unroll
      for (int nt = 0; nt < 8; ++nt)
        bfr[nt] = *(const short8*)(wst + (nt * 16 + nl) * 264 + ko);
#pragma unroll
      for (int mtt = 0; mtt < 2; ++mtt) {
        short8 a = *(const short8*)(ys + ((wave * 2 + mtt) * 16 + nl) * 264 + ko);
#pragma unroll
        for (int nt = 0; nt < 8; ++nt)
          acc[mtt][nt] = __builtin_amdgcn_mfma_f32_16x16x32_bf16(a, bfr[nt], acc[mtt][nt], 0, 0, 0);
      }
    }
    __syncthreads();
  }

#pragma unroll
  for (int mtt = 0; mtt < 2; ++mtt) {
#pragma unroll
    for (int nt = 0; nt < 8; ++nt) {
      int col = nt * 16 + nl;
      float bo = bout[col];
      int rowb = m0 + (wave * 2 + mtt) * 16 + q16 * 4;
#pragma unroll
      for (int r = 0; r < 4; ++r)
        out[(size_t)(rowb + r) * O_SZ + col] = acc[mtt][nt][r] + bo;
    }
  }
}

extern "C" void kernel_launch(void* const* d_in, const int* in_sizes, int n_in,
                              void* d_out, int out_size, void* d_ws, size_t ws_size,
                              hipStream_t stream) {
  const float* x    = (const float*)d_in[0];
  const float* WihF = (const float*)d_in[1];
  const float* WhhF = (const float*)d_in[2];
  const float* bihF = (const float*)d_in[3];
  const float* bhhF = (const float*)d_in[4];
  const float* WihB = (const float*)d_in[5];
  const float* WhhB = (const float*)d_in[6];
  const float* bihB = (const float*)d_in[7];
  const float* bhhB = (const float*)d_in[8];
  const float* Wout = (const float*)d_in[9];
  const float* bout = (const float*)d_in[10];
  float* out = (float*)d_out;
  unsigned char* ws = (unsigned char*)d_ws;

  hipMemsetAsync(ws, 0, (size_t)MEMSET_BYTES, stream);
  cvt_x<<<8192, 256, 0, stream>>>(x, (unsigned short*)(ws + XBF_OFF));
  lstm_scan<<<128, 512, 0, stream>>>((const unsigned short*)(ws + XBF_OFF),
                                     WihF, WhhF, bihF, bhhF,
                                     WihB, WhhB, bihB, bhhB,
                                     ws, out);
  proj<<<512, 256, 0, stream>>>((const unsigned short*)(ws + Y_OFF), Wout, bout, out);
}

// Round 6
// 3258.685 us; speedup vs baseline: 1.1656x; 1.1656x over previous
//
#include <hip/hip_runtime.h>
#include <stdint.h>

#define T_LEN 1024
#define B_SZ  64
#define I_SZ  256
#define H_SZ  512
#define O_SZ  128

// workspace layout (bytes)
#define HB_OFF  0ull                  // 2 bufs * 2 dir * 64 * 512 * 4B = 1048576 (tagged h words)
#define Y_OFF   1048576ull            // 64*1024*1024*2 = 134217728
#define XBF_OFF 135266304ull          // 64*1024*256*2  = 33554432
#define MEMSET_BYTES 1048576ull       // tagged h buffers (memset tag 0 == step-0 expectation)

typedef __attribute__((ext_vector_type(8))) short short8;
typedef __attribute__((ext_vector_type(4))) float f32x4;

__device__ __forceinline__ unsigned short f2bf(float f) {
  unsigned u = __float_as_uint(f);
  u += 0x7fffu + ((u >> 16) & 1u);
  return (unsigned short)(u >> 16);
}
__device__ __forceinline__ ushort4 cvt4(float4 v) {
  ushort4 p;
  p.x = f2bf(v.x); p.y = f2bf(v.y); p.z = f2bf(v.z); p.w = f2bf(v.w);
  return p;
}
__device__ __forceinline__ float sigm(float x) { return 1.0f / (1.0f + __expf(-x)); }
__device__ __forceinline__ float tanh_f(float x) { return 1.0f - 2.0f / (1.0f + __expf(2.0f * x)); }

// ---------------- input fp32 -> bf16 conversion ----------------
__global__ void __launch_bounds__(256) cvt_x(const float* __restrict__ x,
                                             unsigned short* __restrict__ xb) {
  size_t i = ((size_t)blockIdx.x * 256 + threadIdx.x) * 8;
  float4 a = *(const float4*)(x + i);
  float4 b = *(const float4*)(x + i + 4);
  *(ushort4*)(xb + i)     = cvt4(a);
  *(ushort4*)(xb + i + 4) = cvt4(b);
}

// ---------------- persistent bidirectional LSTM scan ----------------
// grid 128 = 8 chains (dir x 4 batch-groups of 16) x 16 unit-group WGs (32
// units each), 512 thr. R5 shape, but h exchange via SELF-ANNOUNCING tagged
// u32 words: word = (h_bf16 << 16) | step_tag, stored/loaded with the
// PROVEN u32 agent-scope atomics (sc1 path). Tag travels inside the word so
// no drain, no flags, no fences: consumer polls the data words until
// tag == s; ping-pong reuse gated by observed-tag data dependences.
__global__ void __launch_bounds__(512, 2)
lstm_scan(const unsigned short* __restrict__ xbf,
          const float* __restrict__ WihF, const float* __restrict__ WhhF,
          const float* __restrict__ bihF, const float* __restrict__ bhhF,
          const float* __restrict__ WihB, const float* __restrict__ WhhB,
          const float* __restrict__ bihB, const float* __restrict__ bhhB,
          unsigned char* __restrict__ ws, float* __restrict__ out)
{
  __shared__ unsigned short xs[2][16][264];  // x double buffer (16 batch x 256)
  __shared__ unsigned short hs[16][520];     // h staging (16 batch x 512)
  __shared__ float gbuf[4][16][36];          // [gate][batch][unit 0..31]
  __shared__ float cst[16][36];              // cell state fp32

  const int tid  = threadIdx.x;
  const int lane = tid & 63;
  const int wave = tid >> 6;
  const int nl   = lane & 15;
  const int q16  = lane >> 4;

  const int wg = blockIdx.x;
  const int d  = wg >> 6;              // 0 fwd, 1 bwd
  const int b0 = ((wg >> 4) & 3) * 16; // batch-group base (16 batches)
  const int u0 = (wg & 15) * 32;       // unit-group base (32 units)

  const float* Wih = d ? WihB : WihF;
  const float* Whh = d ? WhhB : WhhF;
  const float* bih = d ? bihB : bihF;
  const float* bhh = d ? bhhB : bhhF;

  const int gate = wave >> 1;          // 0=i 1=f 2=g 3=o
  const int usub = (wave & 1) * 16;    // which 16 of the WG's 32 units

  // ---- preload B fragments: wfrag[0..7]=Wih(K=256), [8..23]=Whh(K=512) ----
  short8 wfrag[24];
  {
    const int row = gate * H_SZ + u0 + usub + nl;
    const float* wi = Wih + (size_t)row * I_SZ;
    const float* wh = Whh + (size_t)row * H_SZ;
#pragma unroll
    for (int kk = 0; kk < 24; ++kk) {
      const float* src = (kk < 8) ? (wi + kk * 32 + q16 * 8)
                                  : (wh + (kk - 8) * 32 + q16 * 8);
      float4 v0 = ((const float4*)src)[0];
      float4 v1 = ((const float4*)src)[1];
      short8 w;
      w[0] = (short)f2bf(v0.x); w[1] = (short)f2bf(v0.y);
      w[2] = (short)f2bf(v0.z); w[3] = (short)f2bf(v0.w);
      w[4] = (short)f2bf(v1.x); w[5] = (short)f2bf(v1.y);
      w[6] = (short)f2bf(v1.z); w[7] = (short)f2bf(v1.w);
      wfrag[kk] = w;
    }
  }
  const float bias = bih[gate * H_SZ + u0 + usub + nl] + bhh[gate * H_SZ + u0 + usub + nl];

  cst[tid >> 5][tid & 31] = 0.0f;

  unsigned* hbuf32 = (unsigned*)(ws + HB_OFF);
  unsigned* ybuf32 = (unsigned*)(ws + Y_OFF);
  unsigned* hs32   = (unsigned*)hs;

  const int sm = tid >> 5, sseg = tid & 31;  // x-staging coords (16 x 32)

  // ---- prologue: stage x(t0) into xs[0], xacc for s=0, prefetch x(t1) ----
  {
    const int t0 = d ? (T_LEN - 1) : 0;
    uint4 a = *(const uint4*)(xbf + ((size_t)(b0 + sm) * T_LEN + t0) * I_SZ + sseg * 8);
    *(uint4*)(&xs[0][sm][sseg * 8]) = a;
  }
  __syncthreads();
  f32x4 xacc = {0.f, 0.f, 0.f, 0.f};
  {
    const unsigned short* xr = &xs[0][nl][q16 * 8];
#pragma unroll
    for (int kk = 0; kk < 8; ++kk) {
      short8 a = *(const short8*)(xr + kk * 32);
      xacc = __builtin_amdgcn_mfma_f32_16x16x32_bf16(a, wfrag[kk], xacc, 0, 0, 0);
    }
  }
  uint4 px;
  {
    const int t1 = d ? (T_LEN - 2) : 1;
    px = *(const uint4*)(xbf + ((size_t)(b0 + sm) * T_LEN + t1) * I_SZ + sseg * 8);
  }

  for (int s = 0; s < T_LEN; ++s) {
    const int t   = d ? (T_LEN - 1 - s) : s;
    const int cur = s & 1, nxt = cur ^ 1;
    const int rb  = cur ^ 1, wb = cur;

    // ---- load tagged h_{s-1}: 8 pairs (16 u32) per thread ----
    unsigned wlo[8], whi[8];
    const unsigned* hb = hbuf32 + (size_t)((rb * 2 + d) * B_SZ + b0) * 512;
#pragma unroll
    for (int j = 0; j < 8; ++j) {
      int lin2 = j * 512 + tid;            // pair index 0..4095
      int m = lin2 >> 8, p = lin2 & 255;
      wlo[j] = __hip_atomic_load(hb + m * 512 + 2 * p,     __ATOMIC_RELAXED, __HIP_MEMORY_SCOPE_AGENT);
      whi[j] = __hip_atomic_load(hb + m * 512 + 2 * p + 1, __ATOMIC_RELAXED, __HIP_MEMORY_SCOPE_AGENT);
    }
    // stage next x into xs[nxt] while loads are in flight
    if (s < T_LEN - 1)
      *(uint4*)(&xs[nxt][sm][sseg * 8]) = px;
    // ---- poll: all 16 tags must equal s ----
    {
      const unsigned tag = (unsigned)s;
      for (;;) {
        unsigned bad = 0;
#pragma unroll
        for (int j = 0; j < 8; ++j)
          bad |= (((wlo[j] ^ tag) | (whi[j] ^ tag)) & 0xffffu) ? (1u << j) : 0u;
        if (!bad) break;
#pragma unroll
        for (int j = 0; j < 8; ++j)
          if (bad & (1u << j)) {
            int lin2 = j * 512 + tid;
            int m = lin2 >> 8, p = lin2 & 255;
            wlo[j] = __hip_atomic_load(hb + m * 512 + 2 * p,     __ATOMIC_RELAXED, __HIP_MEMORY_SCOPE_AGENT);
            whi[j] = __hip_atomic_load(hb + m * 512 + 2 * p + 1, __ATOMIC_RELAXED, __HIP_MEMORY_SCOPE_AGENT);
          }
      }
    }
    // ---- payload -> LDS (pack 2 bf16 per dword) ----
#pragma unroll
    for (int j = 0; j < 8; ++j) {
      int lin2 = j * 512 + tid;
      int m = lin2 >> 8, p = lin2 & 255;
      hs32[m * 260 + p] = (wlo[j] >> 16) | (whi[j] & 0xffff0000u);
    }
    __syncthreads();

    // ---- h-part MFMAs (dual chains), seeded with precomputed x-part ----
    f32x4 acc0 = xacc, acc1 = {0.f, 0.f, 0.f, 0.f};
    {
      const unsigned short* ar = &hs[nl][q16 * 8];
#pragma unroll
      for (int kk = 0; kk < 16; kk += 2) {
        short8 a0 = *(const short8*)(ar + kk * 32);
        short8 a1 = *(const short8*)(ar + (kk + 1) * 32);
        acc0 = __builtin_amdgcn_mfma_f32_16x16x32_bf16(a0, wfrag[8 + kk], acc0, 0, 0, 0);
        acc1 = __builtin_amdgcn_mfma_f32_16x16x32_bf16(a1, wfrag[9 + kk], acc1, 0, 0, 0);
      }
      acc0 += acc1;
    }

    // ---- bias + activation -> gbuf ----
#pragma unroll
    for (int r = 0; r < 4; ++r) {
      float v = acc0[r] + bias;
      v = (gate == 2) ? tanh_f(v) : sigm(v);
      gbuf[gate][q16 * 4 + r][usub + nl] = v;
    }
    __syncthreads();

    // ---- cell/hidden update + tagged h store (self-announcing) ----
    {
      int m = tid >> 5, n = tid & 31;
      float gi = gbuf[0][m][n], gf = gbuf[1][m][n];
      float gg = gbuf[2][m][n], go = gbuf[3][m][n];
      float c = gf * cst[m][n] + gi * gg;
      cst[m][n] = c;
      float h = go * tanh_f(c);
      unsigned hbits = f2bf(h);
      // tagged word: payload<<16 | (s+1); tag rides with the data
      __hip_atomic_store(hbuf32 + (size_t)((wb * 2 + d) * B_SZ + b0 + m) * 512 + u0 + n,
                         (hbits << 16) | (unsigned)(s + 1),
                         __ATOMIC_RELAXED, __HIP_MEMORY_SCOPE_AGENT);
      unsigned other = __shfl_xor(hbits, 1);
      if ((tid & 1) == 0) {
        unsigned packed = hbits | (other << 16);
        size_t yi = ((size_t)(b0 + m) * T_LEN + t) * 512 + (d * H_SZ + u0 + n) / 2;
        ybuf32[yi] = packed;
      }
      if (s == T_LEN - 1) {
        size_t hi = (size_t)(d * B_SZ + b0 + m) * H_SZ + u0 + n;
        out[8388608ull + hi] = h;            // h_n
        out[8388608ull + 65536ull + hi] = c; // c_n
      }
    }

    if (s < T_LEN - 1) {
      // ---- prefetch x for s+2 ----
      if (s + 2 < T_LEN) {
        const int t2 = d ? (T_LEN - 3 - s) : (s + 2);
        px = *(const uint4*)(xbf + ((size_t)(b0 + sm) * T_LEN + t2) * I_SZ + sseg * 8);
      }
      // ---- precompute x-part MFMAs for step s+1 (off critical path) ----
      f32x4 xa = {0.f, 0.f, 0.f, 0.f};
      const unsigned short* xr = &xs[nxt][nl][q16 * 8];
#pragma unroll
      for (int kk = 0; kk < 8; ++kk) {
        short8 a = *(const short8*)(xr + kk * 32);
        xa = __builtin_amdgcn_mfma_f32_16x16x32_bf16(a, wfrag[kk], xa, 0, 0, 0);
      }
      xacc = xa;
    }
  }
}

// ---------------- output projection: out = y @ W_out^T + b_out ----------------
__global__ void __launch_bounds__(256, 1)
proj(const unsigned short* __restrict__ y, const float* __restrict__ Wout,
     const float* __restrict__ bout, float* __restrict__ out)
{
  __shared__ unsigned short ys[128 * 264];
  __shared__ unsigned short wst[128 * 264];

  const int tid  = threadIdx.x;
  const int wave = tid >> 6;
  const int lane = tid & 63;
  const int nl   = lane & 15;
  const int q16  = lane >> 4;
  const int m0   = blockIdx.x * 128;

  f32x4 acc[2][8];
#pragma unroll
  for (int a = 0; a < 2; ++a)
#pragma unroll
    for (int b = 0; b < 8; ++b) acc[a][b] = (f32x4){0.f, 0.f, 0.f, 0.f};

  for (int k0 = 0; k0 < 1024; k0 += 256) {
    {
      int r = tid >> 1, half = tid & 1;
      const uint4* src = (const uint4*)(y + (size_t)(m0 + r) * 1024 + k0 + half * 128);
      uint4* dst = (uint4*)(ys + r * 264 + half * 128);
#pragma unroll
      for (int q = 0; q < 16; ++q) dst[q] = src[q];
    }
    {
      int r = tid >> 1, half = tid & 1;
      const float4* src = (const float4*)(Wout + (size_t)r * 1024 + k0 + half * 128);
      unsigned short* wd = wst + r * 264 + half * 128;
#pragma unroll
      for (int q = 0; q < 32; ++q) *(ushort4*)(wd + q * 4) = cvt4(src[q]);
    }
    __syncthreads();

#pragma unroll
    for (int kk = 0; kk < 8; ++kk) {
      const int ko = kk * 32 + q16 * 8;
      short8 bfr[8];
#pragma unroll
      for (int nt = 0; nt < 8; ++nt)
        bfr[nt] = *(const short8*)(wst + (nt * 16 + nl) * 264 + ko);
#pragma unroll
      for (int mtt = 0; mtt < 2; ++mtt) {
        short8 a = *(const short8*)(ys + ((wave * 2 + mtt) * 16 + nl) * 264 + ko);
#pragma unroll
        for (int nt = 0; nt < 8; ++nt)
          acc[mtt][nt] = __builtin_amdgcn_mfma_f32_16x16x32_bf16(a, bfr[nt], acc[mtt][nt], 0, 0, 0);
      }
    }
    __syncthreads();
  }

#pragma unroll
  for (int mtt = 0; mtt < 2; ++mtt) {
#pragma unroll
    for (int nt = 0; nt < 8; ++nt) {
      int col = nt * 16 + nl;
      float bo = bout[col];
      int rowb = m0 + (wave * 2 + mtt) * 16 + q16 * 4;
#pragma unroll
      for (int r = 0; r < 4; ++r)
        out[(size_t)(rowb + r) * O_SZ + col] = acc[mtt][nt][r] + bo;
    }
  }
}

extern "C" void kernel_launch(void* const* d_in, const int* in_sizes, int n_in,
                              void* d_out, int out_size, void* d_ws, size_t ws_size,
                              hipStream_t stream) {
  const float* x    = (const float*)d_in[0];
  const float* WihF = (const float*)d_in[1];
  const float* WhhF = (const float*)d_in[2];
  const float* bihF = (const float*)d_in[3];
  const float* bhhF = (const float*)d_in[4];
  const float* WihB = (const float*)d_in[5];
  const float* WhhB = (const float*)d_in[6];
  const float* bihB = (const float*)d_in[7];
  const float* bhhB = (const float*)d_in[8];
  const float* Wout = (const float*)d_in[9];
  const float* bout = (const float*)d_in[10];
  float* out = (float*)d_out;
  unsigned char* ws = (unsigned char*)d_ws;

  hipMemsetAsync(ws, 0, (size_t)MEMSET_BYTES, stream);
  cvt_x<<<8192, 256, 0, stream>>>(x, (unsigned short*)(ws + XBF_OFF));
  lstm_scan<<<128, 512, 0, stream>>>((const unsigned short*)(ws + XBF_OFF),
                                     WihF, WhhF, bihF, bhhF,
                                     WihB, WhhB, bihB, bhhB,
                                     ws, out);
  proj<<<512, 256, 0, stream>>>((const unsigned short*)(ws + Y_OFF), Wout, bout, out);
}